// Round 1
// baseline (307.435 us; speedup 1.0000x reference)
//
#include <hip/hip_runtime.h>
#include <math.h>

// ---------------------------------------------------------------------------
// FocalLoss: geodetic->ECEF->ENU error -> distance -> focal-weighted RMS.
// Pipeline: init (zero max slot) -> pass1 (dist per element, global max via
// atomicMax on uint bits) -> pass2 (focal weight + sum of squares, per-block
// partials) -> final (reduce partials, sqrt(mean)).
//
// Numerics: deg2rad as single fp32 mul (bit-matches numpy), then the entire
// ECEF/ENU chain in double to avoid fp32 cancellation noise on the
// pred - ref subtraction (ref ~6.4e6 m, d ~2 m). Distance rounded to fp32.
// ---------------------------------------------------------------------------

#define THREADS 256
#define PART_OFF 64
#define PART_CAP 8192
#define DIST_OFF (64 + PART_CAP * 8)   // 65600 bytes

__device__ __forceinline__ float dist_for(const float* __restrict__ inp,
                                          const float* __restrict__ tgt,
                                          long i) {
    float latd = tgt[3 * i + 0];
    float lond = tgt[3 * i + 1];
    float hf   = tgt[3 * i + 2];

    // jnp.deg2rad: fp32 multiply by fp32(pi/180) — single correctly-rounded op.
    const float D2R = (float)0.017453292519943295;
    float latr = latd * D2R;
    float lonr = lond * D2R;

    // Everything below in double: the pred-ref subtraction is catastrophically
    // cancelling in fp32 (6.4e6 vs ~2 m), double keeps us within the np ref's
    // own rounding noise.
    double sl = sin((double)latr), cl = cos((double)latr);
    double so = sin((double)lonr), co = cos((double)lonr);
    double h = (double)hf;

    const double A  = 6378137.0;
    const double E2 = 0.00669437999014;
    double N  = A / sqrt(1.0 - E2 * sl * sl);
    double Nh = N + h;
    double x = Nh * cl * co;
    double y = Nh * cl * so;
    double z = (N * (1.0 - E2) + h) * sl;

    double dx = (double)inp[3 * i + 0] - x;
    double dy = (double)inp[3 * i + 1] - y;
    double dz = (double)inp[3 * i + 2] - z;

    double e = -so * dx + co * dy;
    double n = -sl * co * dx - sl * so * dy + cl * dz;
    double u =  cl * co * dx + cl * so * dy + sl * dz;

    return (float)sqrt(e * e + n * n + u * u);
}

__global__ void k_init(unsigned* maxslot) {
    if (threadIdx.x == 0) *maxslot = 0u;
}

__global__ void k_pass1(const float* __restrict__ inp,
                        const float* __restrict__ tgt,
                        float* __restrict__ dist_arr,   // may be null
                        unsigned* __restrict__ maxslot,
                        long B) {
    long stride = (long)gridDim.x * blockDim.x;
    float lmax = 0.0f;
    for (long i = (long)blockIdx.x * blockDim.x + threadIdx.x; i < B; i += stride) {
        float d = dist_for(inp, tgt, i);
        if (dist_arr) dist_arr[i] = d;
        lmax = fmaxf(lmax, d);
    }
    // wave64 reduce
    for (int off = 32; off > 0; off >>= 1)
        lmax = fmaxf(lmax, __shfl_down(lmax, off, 64));
    if ((threadIdx.x & 63) == 0)
        atomicMax(maxslot, __float_as_uint(lmax));  // dist >= 0: uint order == float order
}

__global__ void k_pass2(const float* __restrict__ dist_arr,  // may be null
                        const float* __restrict__ inp,
                        const float* __restrict__ tgt,
                        const unsigned* __restrict__ maxslot,
                        double* __restrict__ partials,
                        long B) {
    float mx = __uint_as_float(*maxslot);
    float denom = mx + 1e-8f;

    double acc = 0.0;
    long stride = (long)gridDim.x * blockDim.x;
    for (long i = (long)blockIdx.x * blockDim.x + threadIdx.x; i < B; i += stride) {
        float d = dist_arr ? dist_arr[i] : dist_for(inp, tgt, i);
        float g = 2.0f * expf(-d);                 // dynamic gamma (SCALE=1, GAMMA=2)
        // true division like numpy: max element gives ratio <= 1.0 exactly
        float base = 1.0f - sqrtf(d / denom);
        base = fmaxf(base, 0.0f);                  // guard powf(neg, frac) = NaN
        float w = powf(base, g);
        float fl = w * d;                          // ALPHA = 1
        acc += (double)fl * (double)fl;
    }
    for (int off = 32; off > 0; off >>= 1)
        acc += __shfl_down(acc, off, 64);
    __shared__ double lds[THREADS / 64];
    int wave = threadIdx.x >> 6;
    if ((threadIdx.x & 63) == 0) lds[wave] = acc;
    __syncthreads();
    if (threadIdx.x == 0) {
        double s = lds[0];
        for (int w = 1; w < (int)(blockDim.x >> 6); ++w) s += lds[w];
        partials[blockIdx.x] = s;
    }
}

__global__ void k_final(const double* __restrict__ partials, int nparts,
                        float* __restrict__ out, long B) {
    double acc = 0.0;
    for (int i = threadIdx.x; i < nparts; i += blockDim.x) acc += partials[i];
    for (int off = 32; off > 0; off >>= 1)
        acc += __shfl_down(acc, off, 64);
    __shared__ double lds[THREADS / 64];
    int wave = threadIdx.x >> 6;
    if ((threadIdx.x & 63) == 0) lds[wave] = acc;
    __syncthreads();
    if (threadIdx.x == 0) {
        double s = lds[0];
        for (int w = 1; w < (int)(blockDim.x >> 6); ++w) s += lds[w];
        out[0] = (float)sqrt(s / (double)B);
    }
}

extern "C" void kernel_launch(void* const* d_in, const int* in_sizes, int n_in,
                              void* d_out, int out_size, void* d_ws, size_t ws_size,
                              hipStream_t stream) {
    const float* inp = (const float*)d_in[0];   // (B,3) predicted ECEF
    const float* tgt = (const float*)d_in[1];   // (B,3) geodetic lat/lon/h
    float* out = (float*)d_out;
    long B = (long)in_sizes[0] / 3;

    unsigned* maxslot = (unsigned*)d_ws;
    double* partials = (double*)((char*)d_ws + PART_OFF);
    float* dist_arr = nullptr;
    size_t need = (size_t)DIST_OFF + (size_t)B * sizeof(float);
    if (ws_size >= need) dist_arr = (float*)((char*)d_ws + DIST_OFF);

    int nblocks = (int)((B + THREADS * 4 - 1) / ((long)THREADS * 4));
    if (nblocks > PART_CAP) nblocks = PART_CAP;
    if (nblocks < 1) nblocks = 1;

    k_init<<<1, 64, 0, stream>>>(maxslot);
    k_pass1<<<nblocks, THREADS, 0, stream>>>(inp, tgt, dist_arr, maxslot, B);
    k_pass2<<<nblocks, THREADS, 0, stream>>>(dist_arr, inp, tgt, maxslot, partials, B);
    k_final<<<1, THREADS, 0, stream>>>(partials, nblocks, out, B);
}

// Round 3
// 289.516 us; speedup vs baseline: 1.0619x; 1.0619x over previous
//
#include <hip/hip_runtime.h>
#include <math.h>

// ---------------------------------------------------------------------------
// FocalLoss: geodetic->ECEF->ENU error -> distance -> focal-weighted RMS.
// Pipeline: init (zero max slot) -> pass1 (dist per element, global max via
// atomicMax on uint bits) -> pass2 (focal weight + sum of squares, per-block
// partials) -> final (reduce partials, sqrt(mean)).
//
// R1 change: replace libm f64 sin/cos (branchy Payne-Hanek path -> VALUBusy
// 17%) with straight-line Cody-Waite reduction + fdlibm minimax polys
// (args are small: |lat|<=1.4, |lon|<=pi). Replace A/sqrt(w) with seeded
// Newton rsqrt (w in [0.993,1]). Replace powf with exp2(g*log2(b)).
// R2 fix: __exp2f doesn't exist in HIP -> __builtin_amdgcn_exp2f (v_exp_f32).
// ---------------------------------------------------------------------------

#define THREADS 256
#define PART_OFF 64
#define PART_CAP 8192
#define DIST_OFF (64 + PART_CAP * 8)   // 65600 bytes

// Branchless double sincos for |x| <= ~3.15 (no Payne-Hanek).
// Abs error ~1e-16 -> position error ~1e-9 m at N=6.4e6.
__device__ __forceinline__ void sincos_small(double x, double& s_out, double& c_out) {
    const double TWO_OVER_PI = 0.636619772367581343076;
    const double PIO2_HI = 1.57079632679489655800e+00;
    const double PIO2_LO = 6.12323399573676603587e-17;
    double kd = rint(x * TWO_OVER_PI);          // k in {-2..2}
    int q = ((int)kd) & 3;
    double r = fma(-kd, PIO2_HI, x);
    r = fma(-kd, PIO2_LO, r);
    double r2 = r * r;

    // fdlibm __kernel_sin coefficients (|r| <= pi/4)
    double ps = 1.58969099521155010221e-10;
    ps = fma(ps, r2, -2.50507602534068634195e-08);
    ps = fma(ps, r2, 2.75573137070700676789e-06);
    ps = fma(ps, r2, -1.98412698298579493134e-04);
    ps = fma(ps, r2, 8.33333333332248946124e-03);
    ps = fma(ps, r2, -1.66666666666666324348e-01);
    double s = fma(r2 * r, ps, r);

    // fdlibm __kernel_cos coefficients
    double pc = -1.13596475577881948265e-11;
    pc = fma(pc, r2, 2.08757232129817482790e-09);
    pc = fma(pc, r2, -2.75573143513906633035e-07);
    pc = fma(pc, r2, 2.48015872894767294178e-05);
    pc = fma(pc, r2, -1.38888888888741095749e-03);
    pc = fma(pc, r2, 4.16666666666666019037e-02);
    double c = fma(r2 * r2, pc, fma(-0.5, r2, 1.0));

    // quadrant selection (branchless cndmask)
    double sr = (q & 1) ? c : s;
    double cr = (q & 1) ? s : c;
    sr = (q & 2) ? -sr : sr;
    cr = ((q + 1) & 2) ? -cr : cr;
    s_out = sr;
    c_out = cr;
}

__device__ __forceinline__ float dist_for(const float* __restrict__ inp,
                                          const float* __restrict__ tgt,
                                          long i) {
    float latd = tgt[3 * i + 0];
    float lond = tgt[3 * i + 1];
    float hf   = tgt[3 * i + 2];

    // jnp.deg2rad: fp32 multiply by fp32(pi/180) — single correctly-rounded op.
    const float D2R = (float)0.017453292519943295;
    float latr = latd * D2R;
    float lonr = lond * D2R;

    double sl, cl, so, co;
    sincos_small((double)latr, sl, cl);
    sincos_small((double)lonr, so, co);
    double h = (double)hf;

    const double A  = 6378137.0;
    const double E2 = 0.00669437999014;
    // N = A * rsqrt(w), w = 1 - E2*sl^2 in [0.9933, 1].
    // Linear seed y0 = 1.5 - 0.5w (err ~1.7e-5), 2 Newton steps -> ~1e-19.
    double w = fma(-E2 * sl, sl, 1.0);
    double y = fma(-0.5, w, 1.5);
    y = y * fma(-0.5 * w, y * y, 1.5);
    y = y * fma(-0.5 * w, y * y, 1.5);
    double N  = A * y;
    double Nh = N + h;
    double x = Nh * cl * co;
    double yy = Nh * cl * so;
    double z = fma(N, -E2, N + h) * sl;   // (N*(1-E2)+h)*sl

    double dx = (double)inp[3 * i + 0] - x;
    double dy = (double)inp[3 * i + 1] - yy;
    double dz = (double)inp[3 * i + 2] - z;

    double e = -so * dx + co * dy;
    double n = -sl * co * dx - sl * so * dy + cl * dz;
    double u =  cl * co * dx + cl * so * dy + sl * dz;

    return sqrtf((float)(e * e + n * n + u * u));
}

__global__ void k_init(unsigned* maxslot) {
    if (threadIdx.x == 0) *maxslot = 0u;
}

__global__ void k_pass1(const float* __restrict__ inp,
                        const float* __restrict__ tgt,
                        float* __restrict__ dist_arr,   // may be null
                        unsigned* __restrict__ maxslot,
                        long B) {
    long stride = (long)gridDim.x * blockDim.x;
    float lmax = 0.0f;
    for (long i = (long)blockIdx.x * blockDim.x + threadIdx.x; i < B; i += stride) {
        float d = dist_for(inp, tgt, i);
        if (dist_arr) dist_arr[i] = d;
        lmax = fmaxf(lmax, d);
    }
    for (int off = 32; off > 0; off >>= 1)
        lmax = fmaxf(lmax, __shfl_down(lmax, off, 64));
    if ((threadIdx.x & 63) == 0)
        atomicMax(maxslot, __float_as_uint(lmax));  // dist >= 0: uint order == float order
}

__global__ void k_pass2(const float* __restrict__ dist_arr,  // may be null
                        const float* __restrict__ inp,
                        const float* __restrict__ tgt,
                        const unsigned* __restrict__ maxslot,
                        double* __restrict__ partials,
                        long B) {
    float mx = __uint_as_float(*maxslot);
    float denom = mx + 1e-8f;

    double acc = 0.0;
    long stride = (long)gridDim.x * blockDim.x;
    for (long i = (long)blockIdx.x * blockDim.x + threadIdx.x; i < B; i += stride) {
        float d = dist_arr ? dist_arr[i] : dist_for(inp, tgt, i);
        float g = 2.0f * __expf(-d);               // dynamic gamma (SCALE=1, GAMMA=2)
        // true division like numpy: max element gives ratio <= 1.0 exactly
        float base = 1.0f - sqrtf(d / denom);
        base = fmaxf(base, 0.0f);
        // base^g: straight-line HW trans ops. log2(0)=-inf -> exp2(-inf)=0 (correct limit).
        float wgt = __builtin_amdgcn_exp2f(g * __log2f(base));
        float fl = wgt * d;                        // ALPHA = 1
        acc += (double)fl * (double)fl;
    }
    for (int off = 32; off > 0; off >>= 1)
        acc += __shfl_down(acc, off, 64);
    __shared__ double lds[THREADS / 64];
    int wave = threadIdx.x >> 6;
    if ((threadIdx.x & 63) == 0) lds[wave] = acc;
    __syncthreads();
    if (threadIdx.x == 0) {
        double s = lds[0];
        for (int w = 1; w < (int)(blockDim.x >> 6); ++w) s += lds[w];
        partials[blockIdx.x] = s;
    }
}

__global__ void k_final(const double* __restrict__ partials, int nparts,
                        float* __restrict__ out, long B) {
    double acc = 0.0;
    for (int i = threadIdx.x; i < nparts; i += blockDim.x) acc += partials[i];
    for (int off = 32; off > 0; off >>= 1)
        acc += __shfl_down(acc, off, 64);
    __shared__ double lds[THREADS / 64];
    int wave = threadIdx.x >> 6;
    if ((threadIdx.x & 63) == 0) lds[wave] = acc;
    __syncthreads();
    if (threadIdx.x == 0) {
        double s = lds[0];
        for (int w = 1; w < (int)(blockDim.x >> 6); ++w) s += lds[w];
        out[0] = (float)sqrt(s / (double)B);
    }
}

extern "C" void kernel_launch(void* const* d_in, const int* in_sizes, int n_in,
                              void* d_out, int out_size, void* d_ws, size_t ws_size,
                              hipStream_t stream) {
    const float* inp = (const float*)d_in[0];   // (B,3) predicted ECEF
    const float* tgt = (const float*)d_in[1];   // (B,3) geodetic lat/lon/h
    float* out = (float*)d_out;
    long B = (long)in_sizes[0] / 3;

    unsigned* maxslot = (unsigned*)d_ws;
    double* partials = (double*)((char*)d_ws + PART_OFF);
    float* dist_arr = nullptr;
    size_t need = (size_t)DIST_OFF + (size_t)B * sizeof(float);
    if (ws_size >= need) dist_arr = (float*)((char*)d_ws + DIST_OFF);

    int nblocks = (int)((B + THREADS * 4 - 1) / ((long)THREADS * 4));
    if (nblocks > PART_CAP) nblocks = PART_CAP;
    if (nblocks < 1) nblocks = 1;

    k_init<<<1, 64, 0, stream>>>(maxslot);
    k_pass1<<<nblocks, THREADS, 0, stream>>>(inp, tgt, dist_arr, maxslot, B);
    k_pass2<<<nblocks, THREADS, 0, stream>>>(dist_arr, inp, tgt, maxslot, partials, B);
    k_final<<<1, THREADS, 0, stream>>>(partials, nblocks, out, B);
}

// Round 4
// 134.151 us; speedup vs baseline: 2.2917x; 2.1581x over previous
//
#include <hip/hip_runtime.h>
#include <math.h>

// ---------------------------------------------------------------------------
// FocalLoss: geodetic->ECEF->ENU error -> distance -> focal-weighted RMS.
// Pipeline: pass1 (dist per 4-elem group, per-block max) -> k_max (reduce
// block maxes) -> pass2 (focal weight + sum of squares, per-block partials)
// -> final (reduce partials, sqrt(mean)).
//
// R4: structural rewrite, math identical to R3 (isolate one variable).
//  - R3 evidence: VALU work halved (17.5%->8.0% busy), dur unchanged 190us,
//    HBM 4% -> latency-bound, zero ILP (VGPR_Count=32, rolled loop,
//    stride-12 scalar loads) + 15.6k same-address atomicMax serialization.
//  - Fix: 1 thread = 4 consecutive elements via 3x float4 loads per array,
//    4 independent f64 chains (forces ILP + outstanding loads); per-block
//    max array + tiny reduce kernel instead of global atomicMax.
// ---------------------------------------------------------------------------

#define THREADS 256
#define PART_OFF 64
#define PART_CAP 8192
#define DIST_OFF (64 + PART_CAP * 8)   // 65600 bytes, 16B-aligned

// Branchless double sincos for |x| <= ~3.15 (no Payne-Hanek).
// Abs error ~1e-16 -> position error ~1e-9 m at N=6.4e6.
__device__ __forceinline__ void sincos_small(double x, double& s_out, double& c_out) {
    const double TWO_OVER_PI = 0.636619772367581343076;
    const double PIO2_HI = 1.57079632679489655800e+00;
    const double PIO2_LO = 6.12323399573676603587e-17;
    double kd = rint(x * TWO_OVER_PI);          // k in {-2..2}
    int q = ((int)kd) & 3;
    double r = fma(-kd, PIO2_HI, x);
    r = fma(-kd, PIO2_LO, r);
    double r2 = r * r;

    double ps = 1.58969099521155010221e-10;
    ps = fma(ps, r2, -2.50507602534068634195e-08);
    ps = fma(ps, r2, 2.75573137070700676789e-06);
    ps = fma(ps, r2, -1.98412698298579493134e-04);
    ps = fma(ps, r2, 8.33333333332248946124e-03);
    ps = fma(ps, r2, -1.66666666666666324348e-01);
    double s = fma(r2 * r, ps, r);

    double pc = -1.13596475577881948265e-11;
    pc = fma(pc, r2, 2.08757232129817482790e-09);
    pc = fma(pc, r2, -2.75573143513906633035e-07);
    pc = fma(pc, r2, 2.48015872894767294178e-05);
    pc = fma(pc, r2, -1.38888888888741095749e-03);
    pc = fma(pc, r2, 4.16666666666666019037e-02);
    double c = fma(r2 * r2, pc, fma(-0.5, r2, 1.0));

    double sr = (q & 1) ? c : s;
    double cr = (q & 1) ? s : c;
    sr = (q & 2) ? -sr : sr;
    cr = ((q + 1) & 2) ? -cr : cr;
    s_out = sr;
    c_out = cr;
}

__device__ __forceinline__ float dist_one(float latd, float lond, float hf,
                                          float px, float py, float pz) {
    const float D2R = (float)0.017453292519943295;  // fp32 deg2rad, matches numpy
    float latr = latd * D2R;
    float lonr = lond * D2R;

    double sl, cl, so, co;
    sincos_small((double)latr, sl, cl);
    sincos_small((double)lonr, so, co);
    double h = (double)hf;

    const double A  = 6378137.0;
    const double E2 = 0.00669437999014;
    double w = fma(-E2 * sl, sl, 1.0);          // in [0.9933, 1]
    double y = fma(-0.5, w, 1.5);               // linear rsqrt seed
    y = y * fma(-0.5 * w, y * y, 1.5);          // 2 Newton steps -> ~1e-19
    y = y * fma(-0.5 * w, y * y, 1.5);
    double N  = A * y;
    double Nh = N + h;
    double x  = Nh * cl * co;
    double yy = Nh * cl * so;
    double z  = fma(N, -E2, N + h) * sl;        // (N*(1-E2)+h)*sl

    double dx = (double)px - x;
    double dy = (double)py - yy;
    double dz = (double)pz - z;

    double e = -so * dx + co * dy;
    double n = -sl * co * dx - sl * so * dy + cl * dz;
    double u =  cl * co * dx + cl * so * dy + sl * dz;

    return sqrtf((float)(e * e + n * n + u * u));
}

__global__ void k_pass1(const float* __restrict__ inp,
                        const float* __restrict__ tgt,
                        float* __restrict__ dist_arr,   // may be null
                        float* __restrict__ blockmax,
                        long B) {
    long ngroups = (B + 3) >> 2;
    long gstride = (long)gridDim.x * blockDim.x;
    float lmax = 0.0f;
    for (long g = (long)blockIdx.x * blockDim.x + threadIdx.x; g < ngroups; g += gstride) {
        long base = g << 2;
        if (base + 3 < B) {
            const float4* t4 = (const float4*)(tgt + 3 * base);   // 48B/group, 16B aligned
            float4 ta = t4[0], tb = t4[1], tc = t4[2];
            const float4* p4 = (const float4*)(inp + 3 * base);
            float4 pa = p4[0], pb = p4[1], pc = p4[2];
            float d0 = dist_one(ta.x, ta.y, ta.z, pa.x, pa.y, pa.z);
            float d1 = dist_one(ta.w, tb.x, tb.y, pa.w, pb.x, pb.y);
            float d2 = dist_one(tb.z, tb.w, tc.x, pb.z, pb.w, pc.x);
            float d3 = dist_one(tc.y, tc.z, tc.w, pc.y, pc.z, pc.w);
            if (dist_arr) *(float4*)(dist_arr + base) = make_float4(d0, d1, d2, d3);
            lmax = fmaxf(lmax, fmaxf(fmaxf(d0, d1), fmaxf(d2, d3)));
        } else {
            for (long i = base; i < B; ++i) {
                float d = dist_one(tgt[3*i], tgt[3*i+1], tgt[3*i+2],
                                   inp[3*i], inp[3*i+1], inp[3*i+2]);
                if (dist_arr) dist_arr[i] = d;
                lmax = fmaxf(lmax, d);
            }
        }
    }
    for (int off = 32; off > 0; off >>= 1)
        lmax = fmaxf(lmax, __shfl_down(lmax, off, 64));
    __shared__ float smax[THREADS / 64];
    if ((threadIdx.x & 63) == 0) smax[threadIdx.x >> 6] = lmax;
    __syncthreads();
    if (threadIdx.x == 0) {
        float m = smax[0];
        for (int w = 1; w < THREADS / 64; ++w) m = fmaxf(m, smax[w]);
        blockmax[blockIdx.x] = m;
    }
}

__global__ void k_max(const float* __restrict__ blockmax, int n,
                      float* __restrict__ maxslot) {
    float m = 0.0f;
    for (int i = threadIdx.x; i < n; i += blockDim.x) m = fmaxf(m, blockmax[i]);
    for (int off = 32; off > 0; off >>= 1)
        m = fmaxf(m, __shfl_down(m, off, 64));
    __shared__ float smax[THREADS / 64];
    if ((threadIdx.x & 63) == 0) smax[threadIdx.x >> 6] = m;
    __syncthreads();
    if (threadIdx.x == 0) {
        float mm = smax[0];
        for (int w = 1; w < THREADS / 64; ++w) mm = fmaxf(mm, smax[w]);
        *maxslot = mm;
    }
}

__device__ __forceinline__ double focal2(float d, float denom) {
    float g = 2.0f * __expf(-d);                  // dynamic gamma (SCALE=1, GAMMA=2)
    float b = 1.0f - sqrtf(d / denom);            // true div: max elem ratio <= 1
    b = fmaxf(b, 0.0f);
    float wgt = __builtin_amdgcn_exp2f(g * __log2f(b));  // b^g; log2(0)->-inf->0 ok
    float fl = wgt * d;                           // ALPHA = 1
    return (double)fl * (double)fl;
}

__global__ void k_pass2(const float* __restrict__ dist_arr,  // may be null
                        const float* __restrict__ inp,
                        const float* __restrict__ tgt,
                        const float* __restrict__ maxslot,
                        double* __restrict__ partials,
                        long B) {
    float denom = *maxslot + 1e-8f;
    long ngroups = (B + 3) >> 2;
    long gstride = (long)gridDim.x * blockDim.x;
    double acc = 0.0;
    for (long g = (long)blockIdx.x * blockDim.x + threadIdx.x; g < ngroups; g += gstride) {
        long base = g << 2;
        if (base + 3 < B) {
            float d0, d1, d2, d3;
            if (dist_arr) {
                float4 d4 = *(const float4*)(dist_arr + base);
                d0 = d4.x; d1 = d4.y; d2 = d4.z; d3 = d4.w;
            } else {
                const float4* t4 = (const float4*)(tgt + 3 * base);
                float4 ta = t4[0], tb = t4[1], tc = t4[2];
                const float4* p4 = (const float4*)(inp + 3 * base);
                float4 pa = p4[0], pb = p4[1], pc = p4[2];
                d0 = dist_one(ta.x, ta.y, ta.z, pa.x, pa.y, pa.z);
                d1 = dist_one(ta.w, tb.x, tb.y, pa.w, pb.x, pb.y);
                d2 = dist_one(tb.z, tb.w, tc.x, pb.z, pb.w, pc.x);
                d3 = dist_one(tc.y, tc.z, tc.w, pc.y, pc.z, pc.w);
            }
            acc += focal2(d0, denom) + focal2(d1, denom)
                 + focal2(d2, denom) + focal2(d3, denom);
        } else {
            for (long i = base; i < B; ++i) {
                float d = dist_arr ? dist_arr[i]
                                   : dist_one(tgt[3*i], tgt[3*i+1], tgt[3*i+2],
                                              inp[3*i], inp[3*i+1], inp[3*i+2]);
                acc += focal2(d, denom);
            }
        }
    }
    for (int off = 32; off > 0; off >>= 1)
        acc += __shfl_down(acc, off, 64);
    __shared__ double lds[THREADS / 64];
    if ((threadIdx.x & 63) == 0) lds[threadIdx.x >> 6] = acc;
    __syncthreads();
    if (threadIdx.x == 0) {
        double s = lds[0];
        for (int w = 1; w < THREADS / 64; ++w) s += lds[w];
        partials[blockIdx.x] = s;
    }
}

__global__ void k_final(const double* __restrict__ partials, int nparts,
                        float* __restrict__ out, long B) {
    double acc = 0.0;
    for (int i = threadIdx.x; i < nparts; i += blockDim.x) acc += partials[i];
    for (int off = 32; off > 0; off >>= 1)
        acc += __shfl_down(acc, off, 64);
    __shared__ double lds[THREADS / 64];
    if ((threadIdx.x & 63) == 0) lds[threadIdx.x >> 6] = acc;
    __syncthreads();
    if (threadIdx.x == 0) {
        double s = lds[0];
        for (int w = 1; w < THREADS / 64; ++w) s += lds[w];
        out[0] = (float)sqrt(s / (double)B);
    }
}

extern "C" void kernel_launch(void* const* d_in, const int* in_sizes, int n_in,
                              void* d_out, int out_size, void* d_ws, size_t ws_size,
                              hipStream_t stream) {
    const float* inp = (const float*)d_in[0];   // (B,3) predicted ECEF
    const float* tgt = (const float*)d_in[1];   // (B,3) geodetic lat/lon/h
    float* out = (float*)d_out;
    long B = (long)in_sizes[0] / 3;

    float* maxslot = (float*)d_ws;
    // blockmax (float, pass1/k_max) and partials (double, pass2/final) share
    // the region at PART_OFF: pass2 only writes after k_max consumed blockmax.
    float* blockmax = (float*)((char*)d_ws + PART_OFF);
    double* partials = (double*)((char*)d_ws + PART_OFF);
    float* dist_arr = nullptr;
    size_t need = (size_t)DIST_OFF + (size_t)B * sizeof(float);
    if (ws_size >= need) dist_arr = (float*)((char*)d_ws + DIST_OFF);

    long ngroups = (B + 3) >> 2;
    int nblocks = (int)((ngroups + THREADS - 1) / THREADS);
    if (nblocks > PART_CAP) nblocks = PART_CAP;
    if (nblocks < 1) nblocks = 1;

    k_pass1<<<nblocks, THREADS, 0, stream>>>(inp, tgt, dist_arr, blockmax, B);
    k_max<<<1, THREADS, 0, stream>>>(blockmax, nblocks, maxslot);
    k_pass2<<<nblocks, THREADS, 0, stream>>>(dist_arr, inp, tgt, maxslot, partials, B);
    k_final<<<1, THREADS, 0, stream>>>(partials, nblocks, out, B);
}